// Round 4
// baseline (312.659 us; speedup 1.0000x reference)
//
#include <hip/hip_runtime.h>
#include <hip/hip_bf16.h>
#include <math.h>

#define NN 100000
#define DD 256
#define BB 4096
#define KK 32
#define ZD 128
#define INVTEMP (1.0f/0.07f)
#define HS 264   // LDS row stride for h tile (bf16): 256 + 8 pad -> 2-way conflicts only
#define SIMBLOCKS ((BB/128)*(BB/128))

typedef unsigned short u16;
typedef __attribute__((ext_vector_type(8))) short short8;   // 8 x bf16 (4 VGPRs)
typedef __attribute__((ext_vector_type(4))) float floatx4;  // MFMA acc

__device__ inline u16 f2bf(float f) {
  __hip_bfloat16 h = __float2bfloat16(f);
  return *reinterpret_cast<u16*>(&h);
}

// ---------------------------------------------------------------------------
// prep: blocks [0, 8192) = aggregate (b = blk>>1, view = blk&1);
//       blocks [8192, 8960) = weight convert/transpose + zero rowsum/colsum
//       + zero the sim completion counter.
// ---------------------------------------------------------------------------
__global__ void prep_kernel(const float* __restrict__ nf,
                            const float* __restrict__ rel,
                            const int* __restrict__ nb1, const int* __restrict__ rl1, const int* __restrict__ mk1,
                            const int* __restrict__ nb2, const int* __restrict__ rl2, const int* __restrict__ mk2,
                            const int* __restrict__ self_ids,
                            u16* __restrict__ v1, u16* __restrict__ v2,
                            const float* __restrict__ W1a, const float* __restrict__ W2a,
                            const float* __restrict__ W1b, const float* __restrict__ W2b,
                            u16* __restrict__ W1at, u16* __restrict__ W2at,
                            u16* __restrict__ W1bt, u16* __restrict__ W2bt,
                            float* __restrict__ rowsum, float* __restrict__ colsum,
                            unsigned* __restrict__ done) {
  int blk = blockIdx.x;
  int tid = threadIdx.x;
  if (blk >= 2 * BB) {
    // ---- weight convert + zero path ----
    int cb = blk - 2 * BB;                       // 0..767
    int idx = cb * 256 + tid;
    const float* W; u16* Wt; int N, off;
    if (idx < 65536)       { W = W1a; Wt = W1at; N = 256; off = idx; }
    else if (idx < 131072) { W = W2a; Wt = W2at; N = 256; off = idx - 65536; }
    else if (idx < 163840) { W = W1b; Wt = W1bt; N = 128; off = idx - 131072; }
    else                   { W = W2b; Wt = W2bt; N = 128; off = idx - 163840; }
    int n = off >> 8, k = off & 255;
    Wt[off] = f2bf(W[k * N + n]);
    if (cb < 16)            rowsum[cb * 256 + tid] = 0.f;
    else if (cb < 32)       colsum[(cb - 16) * 256 + tid] = 0.f;
    if (cb == 32 && tid == 0) *done = 0u;
    return;
  }
  // ---- aggregate path ----
  int b = blk >> 1;
  const int *nb, *rl, *mk;
  u16* out;
  if ((blk & 1) == 0) { nb = nb1; rl = rl1; mk = mk1; out = v1; }
  else                { nb = nb2; rl = rl2; mk = mk2; out = v2; }
  int g = tid >> 6, c = tid & 63;

  float ax = 0.f, ay = 0.f, az = 0.f, aw = 0.f;
  int cnt = 0;
#pragma unroll
  for (int kk = 0; kk < 8; ++kk) {
    int k = kk * 4 + g;
    if (mk[b * KK + k]) {                       // wave-uniform branch
      int nid = nb[b * KK + k];
      int rid = rl[b * KK + k];
      float4 m = *(const float4*)(nf + (size_t)nid * DD + c * 4);
      float4 r = *(const float4*)(rel + (size_t)rid * DD + c * 4);
      ax += m.x + r.x; ay += m.y + r.y; az += m.z + r.z; aw += m.w + r.w;
      cnt++;
    }
  }
  __shared__ float sbuf[4][64][4];
  __shared__ int scnt[4];
  sbuf[g][c][0] = ax; sbuf[g][c][1] = ay; sbuf[g][c][2] = az; sbuf[g][c][3] = aw;
  if (c == 0) scnt[g] = cnt;
  __syncthreads();
  if (g == 0) {
    float sx = sbuf[0][c][0] + sbuf[1][c][0] + sbuf[2][c][0] + sbuf[3][c][0];
    float sy = sbuf[0][c][1] + sbuf[1][c][1] + sbuf[2][c][1] + sbuf[3][c][1];
    float sz = sbuf[0][c][2] + sbuf[1][c][2] + sbuf[2][c][2] + sbuf[3][c][2];
    float sw = sbuf[0][c][3] + sbuf[1][c][3] + sbuf[2][c][3] + sbuf[3][c][3];
    int tot = scnt[0] + scnt[1] + scnt[2] + scnt[3];
    float rx, ry, rz, rw;
    if (tot > 0) {
      float inv = 1.0f / (float)tot;
      rx = sx * inv; ry = sy * inv; rz = sz * inv; rw = sw * inv;
    } else {
      float4 s = *(const float4*)(nf + (size_t)self_ids[b] * DD + c * 4);
      rx = s.x; ry = s.y; rz = s.z; rw = s.w;
    }
    union { u16 us[4]; uint2 u2; } pk;
    pk.us[0] = f2bf(rx); pk.us[1] = f2bf(ry); pk.us[2] = f2bf(rz); pk.us[3] = f2bf(rw);
    *(uint2*)(out + (size_t)b * DD + c * 4) = pk.u2;
  }
}

// ---------------------------------------------------------------------------
// Fused projection + row-normalize:
//   z = relu(v @ Wa + ba) @ Wb + bb;  z_bf16 = z / ||z||_row
// Block = 128 rows x all 128 z-cols -> full rows live in the block, so the
// norm is a block-local reduction (shfl over m16 + LDS across the 2 wave-cols).
// grid (BB/128, 2): blockIdx.y = view.
// ---------------------------------------------------------------------------
__global__ void __launch_bounds__(256, 1)
proj_fused(const u16* __restrict__ v1, const u16* __restrict__ v2,
           const u16* __restrict__ W1at, const u16* __restrict__ W2at,
           const float* __restrict__ b1a, const float* __restrict__ b2a,
           const u16* __restrict__ W1bt, const u16* __restrict__ W2bt,
           const float* __restrict__ b1b, const float* __restrict__ b2b,
           u16* __restrict__ z1, u16* __restrict__ z2) {
  const u16 *v, *Wat, *Wbt;
  const float *ba, *bb;
  u16* z;
  if (blockIdx.y == 0) { v = v1; Wat = W1at; ba = b1a; Wbt = W1bt; bb = b1b; z = z1; }
  else                 { v = v2; Wat = W2at; ba = b2a; Wbt = W2bt; bb = b2b; z = z2; }
  __shared__ u16 hs[128 * HS];
  __shared__ float ns[128][2];
  int tid = threadIdx.x;
  int lane = tid & 63, wid = tid >> 6;
  int m16 = lane & 15, q = lane >> 4;
  int rh = wid >> 1, ch = wid & 1;
  int M0 = blockIdx.x * 128;
  int rowl = rh * 64;                 // block-local row base for this wave

  // ---- phase 1: h = relu(v @ Wa + ba), two 128-col tiles -> LDS ----
  for (int nt = 0; nt < 2; ++nt) {
    int colb = nt * 128 + ch * 64;
    floatx4 acc[4][4] = {};
    for (int k0 = 0; k0 < DD; k0 += 32) {
      short8 a[4], b[4];
#pragma unroll
      for (int i = 0; i < 4; i++)
        a[i] = *(const short8*)(v + (size_t)(M0 + rowl + i * 16 + m16) * DD + k0 + q * 8);
#pragma unroll
      for (int j = 0; j < 4; j++)
        b[j] = *(const short8*)(Wat + (size_t)(colb + j * 16 + m16) * DD + k0 + q * 8);
#pragma unroll
      for (int i = 0; i < 4; i++)
#pragma unroll
        for (int j = 0; j < 4; j++)
          acc[i][j] = __builtin_amdgcn_mfma_f32_16x16x32_bf16(a[i], b[j], acc[i][j], 0, 0, 0);
    }
#pragma unroll
    for (int i = 0; i < 4; i++)
#pragma unroll
      for (int j = 0; j < 4; j++) {
        int col = colb + j * 16 + m16;
        float bv = ba[col];
#pragma unroll
        for (int r = 0; r < 4; r++) {
          int row = rowl + i * 16 + q * 4 + r;
          hs[row * HS + col] = f2bf(fmaxf(acc[i][j][r] + bv, 0.f));
        }
      }
  }
  __syncthreads();

  // ---- phase 2: z = h @ Wb + bb (128 cols), keep fp32 in registers ----
  int colb = ch * 64;
  floatx4 acc[4][4] = {};
  for (int k0 = 0; k0 < DD; k0 += 32) {
    short8 a[4], b[4];
#pragma unroll
    for (int i = 0; i < 4; i++)
      a[i] = *(const short8*)(hs + (rowl + i * 16 + m16) * HS + k0 + q * 8);
#pragma unroll
    for (int j = 0; j < 4; j++)
      b[j] = *(const short8*)(Wbt + (size_t)(colb + j * 16 + m16) * DD + k0 + q * 8);
#pragma unroll
    for (int i = 0; i < 4; i++)
#pragma unroll
      for (int j = 0; j < 4; j++)
        acc[i][j] = __builtin_amdgcn_mfma_f32_16x16x32_bf16(a[i], b[j], acc[i][j], 0, 0, 0);
  }
  // add bias in place, accumulate row sum-of-squares for this col-half
  float ss[4][4];                     // [i][r]
#pragma unroll
  for (int i = 0; i < 4; i++)
#pragma unroll
    for (int r = 0; r < 4; r++) ss[i][r] = 0.f;
#pragma unroll
  for (int j = 0; j < 4; j++) {
    float bv = bb[colb + j * 16 + m16];
#pragma unroll
    for (int i = 0; i < 4; i++)
#pragma unroll
      for (int r = 0; r < 4; r++) {
        float zv = acc[i][j][r] + bv;
        acc[i][j][r] = zv;
        ss[i][r] += zv * zv;
      }
  }
  // reduce over the 16 cols held across m16 lanes
#pragma unroll
  for (int off = 1; off <= 8; off <<= 1)
#pragma unroll
    for (int i = 0; i < 4; i++)
#pragma unroll
      for (int r = 0; r < 4; r++) ss[i][r] += __shfl_xor(ss[i][r], off);
  if (m16 == 0) {
#pragma unroll
    for (int i = 0; i < 4; i++)
#pragma unroll
      for (int r = 0; r < 4; r++) ns[rowl + i * 16 + q * 4 + r][ch] = ss[i][r];
  }
  __syncthreads();
  // normalize + write bf16
#pragma unroll
  for (int i = 0; i < 4; i++)
#pragma unroll
    for (int r = 0; r < 4; r++) {
      int row = rowl + i * 16 + q * 4 + r;
      float rn = rsqrtf(ns[row][0] + ns[row][1]);
#pragma unroll
      for (int j = 0; j < 4; j++)
        z[(size_t)(M0 + row) * ZD + colb + j * 16 + m16] = f2bf(acc[i][j][r] * rn);
    }
}

// ---------------------------------------------------------------------------
// sim + diag + (last block) loss.
// exp((z1n.z2n^T)/TEMP) row/col sums via shuffle + atomics; diagonal tiles
// write diag = sim_ii (fp32, pre-exp). Last-done block computes the loss with
// atomic-read loads (cross-XCD safe) and writes d_out.
// ---------------------------------------------------------------------------
__global__ void __launch_bounds__(256, 2)
sim_kernel(const u16* __restrict__ z1, const u16* __restrict__ z2,
           float* __restrict__ rowsum, float* __restrict__ colsum,
           float* __restrict__ diag, unsigned* __restrict__ done,
           float* __restrict__ out) {
  int tid = threadIdx.x;
  int lane = tid & 63, wid = tid >> 6;
  int m16 = lane & 15, q = lane >> 4;
  int rowbase = blockIdx.x * 128 + (wid >> 1) * 64;
  int colbase = blockIdx.y * 128 + (wid & 1) * 64;
  floatx4 acc[4][4] = {};
  for (int k0 = 0; k0 < ZD; k0 += 32) {
    short8 a[4], b[4];
#pragma unroll
    for (int i = 0; i < 4; i++)
      a[i] = *(const short8*)(z1 + (size_t)(rowbase + i * 16 + m16) * ZD + k0 + q * 8);
#pragma unroll
    for (int j = 0; j < 4; j++)
      b[j] = *(const short8*)(z2 + (size_t)(colbase + j * 16 + m16) * ZD + k0 + q * 8);
#pragma unroll
    for (int i = 0; i < 4; i++)
#pragma unroll
      for (int j = 0; j < 4; j++)
        acc[i][j] = __builtin_amdgcn_mfma_f32_16x16x32_bf16(a[i], b[j], acc[i][j], 0, 0, 0);
  }
  // diag on diagonal wave-tiles (row==col): i==j and m16 == q*4+r
  if (rowbase == colbase) {
#pragma unroll
    for (int i = 0; i < 4; i++)
#pragma unroll
      for (int r = 0; r < 4; r++)
        if (m16 == q * 4 + r)
          diag[rowbase + i * 16 + m16] = acc[i][i][r] * INVTEMP;
  }
  float rowacc[4][4] = {};   // [i][r]
  float colacc[4] = {};      // [j]
#pragma unroll
  for (int i = 0; i < 4; i++)
#pragma unroll
    for (int j = 0; j < 4; j++)
#pragma unroll
      for (int r = 0; r < 4; r++) {
        float e = __expf(acc[i][j][r] * INVTEMP);
        rowacc[i][r] += e;
        colacc[j] += e;
      }
#pragma unroll
  for (int off = 1; off <= 8; off <<= 1)
#pragma unroll
    for (int i = 0; i < 4; i++)
#pragma unroll
      for (int r = 0; r < 4; r++) rowacc[i][r] += __shfl_xor(rowacc[i][r], off);
  if (m16 == 0) {
#pragma unroll
    for (int i = 0; i < 4; i++)
#pragma unroll
      for (int r = 0; r < 4; r++)
        atomicAdd(&rowsum[rowbase + i * 16 + q * 4 + r], rowacc[i][r]);
  }
#pragma unroll
  for (int off = 16; off <= 32; off <<= 1)
#pragma unroll
    for (int j = 0; j < 4; j++) colacc[j] += __shfl_xor(colacc[j], off);
  if (q == 0) {
#pragma unroll
    for (int j = 0; j < 4; j++)
      atomicAdd(&colsum[colbase + j * 16 + m16], colacc[j]);
  }

  // ---- last-done block computes the loss ----
  __shared__ unsigned lastflag;
  __threadfence();
  if (tid == 0) {
    unsigned old = atomicAdd(done, 1u);
    lastflag = (old == SIMBLOCKS - 1) ? 1u : 0u;
  }
  __syncthreads();
  if (lastflag) {
    __threadfence();                            // acquire
    float acc2 = 0.f;
    for (int i = tid; i < BB; i += 256) {
      float rs = atomicAdd(&rowsum[i], 0.f);    // coherent read
      float cs = atomicAdd(&colsum[i], 0.f);
      float dg = atomicAdd(&diag[i], 0.f);
      acc2 += 0.5f * (__logf(rs) + __logf(cs)) - dg;
    }
#pragma unroll
    for (int off = 1; off < 64; off <<= 1) acc2 += __shfl_xor(acc2, off);
    __shared__ float sred[4];
    if ((tid & 63) == 0) sred[tid >> 6] = acc2;
    __syncthreads();
    if (tid == 0) out[0] = (sred[0] + sred[1] + sred[2] + sred[3]) * (1.0f / BB);
  }
}

extern "C" void kernel_launch(void* const* d_in, const int* in_sizes, int n_in,
                              void* d_out, int out_size, void* d_ws, size_t ws_size,
                              hipStream_t stream) {
  const float* nf  = (const float*)d_in[0];
  const float* rel = (const float*)d_in[1];
  const int* nb1 = (const int*)d_in[2];
  const int* rl1 = (const int*)d_in[3];
  const int* mk1 = (const int*)d_in[4];
  const int* nb2 = (const int*)d_in[5];
  const int* rl2 = (const int*)d_in[6];
  const int* mk2 = (const int*)d_in[7];
  const int* self_ids = (const int*)d_in[8];
  const float* W1a = (const float*)d_in[9];
  const float* b1a = (const float*)d_in[10];
  const float* W1b = (const float*)d_in[11];
  const float* b1b = (const float*)d_in[12];
  const float* W2a = (const float*)d_in[13];
  const float* b2a = (const float*)d_in[14];
  const float* W2b = (const float*)d_in[15];
  const float* b2b = (const float*)d_in[16];

  char* ws = (char*)d_ws;
  u16* v1   = (u16*)ws;                 ws += (size_t)BB * DD * 2;
  u16* v2   = (u16*)ws;                 ws += (size_t)BB * DD * 2;
  u16* z1   = (u16*)ws;                 ws += (size_t)BB * ZD * 2;
  u16* z2   = (u16*)ws;                 ws += (size_t)BB * ZD * 2;
  u16* W1at = (u16*)ws;                 ws += (size_t)DD * DD * 2;
  u16* W2at = (u16*)ws;                 ws += (size_t)DD * DD * 2;
  u16* W1bt = (u16*)ws;                 ws += (size_t)ZD * DD * 2;
  u16* W2bt = (u16*)ws;                 ws += (size_t)ZD * DD * 2;
  float* rowsum = (float*)ws;           ws += (size_t)BB * 4;
  float* colsum = (float*)ws;           ws += (size_t)BB * 4;
  float* diag   = (float*)ws;           ws += (size_t)BB * 4;
  unsigned* done = (unsigned*)ws;       ws += 64;

  prep_kernel<<<2 * BB + 768, 256, 0, stream>>>(nf, rel, nb1, rl1, mk1, nb2, rl2, mk2,
                                                self_ids, v1, v2,
                                                W1a, W2a, W1b, W2b,
                                                W1at, W2at, W1bt, W2bt,
                                                rowsum, colsum, done);
  proj_fused<<<dim3(BB / 128, 2), 256, 0, stream>>>(v1, v2, W1at, W2at, b1a, b2a,
                                                    W1bt, W2bt, b1b, b2b, z1, z2);
  sim_kernel<<<dim3(BB / 128, BB / 128), 256, 0, stream>>>(z1, z2, rowsum, colsum,
                                                           diag, done, (float*)d_out);
}

// Round 5
// 248.927 us; speedup vs baseline: 1.2560x; 1.2560x over previous
//
#include <hip/hip_runtime.h>
#include <hip/hip_bf16.h>
#include <math.h>

#define NN 100000
#define DD 256
#define BB 4096
#define KK 32
#define ZD 128
#define INVTEMP (1.0f/0.07f)
#define HS 264   // LDS row stride for h tile (bf16): 256 + 8 pad -> 2-way conflicts only

typedef unsigned short u16;
typedef __attribute__((ext_vector_type(8))) short short8;   // 8 x bf16 (4 VGPRs)
typedef __attribute__((ext_vector_type(4))) float floatx4;  // MFMA acc

__device__ inline u16 f2bf(float f) {
  __hip_bfloat16 h = __float2bfloat16(f);
  return *reinterpret_cast<u16*>(&h);
}

// ---------------------------------------------------------------------------
// prep: blocks [0, 8192) = aggregate (b = blk>>1, view = blk&1);
//       blocks [8192, 8960) = weight convert/transpose + zero rowsum/colsum.
// ---------------------------------------------------------------------------
__global__ void prep_kernel(const float* __restrict__ nf,
                            const float* __restrict__ rel,
                            const int* __restrict__ nb1, const int* __restrict__ rl1, const int* __restrict__ mk1,
                            const int* __restrict__ nb2, const int* __restrict__ rl2, const int* __restrict__ mk2,
                            const int* __restrict__ self_ids,
                            u16* __restrict__ v1, u16* __restrict__ v2,
                            const float* __restrict__ W1a, const float* __restrict__ W2a,
                            const float* __restrict__ W1b, const float* __restrict__ W2b,
                            u16* __restrict__ W1at, u16* __restrict__ W2at,
                            u16* __restrict__ W1bt, u16* __restrict__ W2bt,
                            float* __restrict__ rowsum, float* __restrict__ colsum) {
  int blk = blockIdx.x;
  int tid = threadIdx.x;
  if (blk >= 2 * BB) {
    // ---- weight convert + zero path ----
    int cb = blk - 2 * BB;                       // 0..767
    int idx = cb * 256 + tid;
    const float* W; u16* Wt; int N, off;
    if (idx < 65536)       { W = W1a; Wt = W1at; N = 256; off = idx; }
    else if (idx < 131072) { W = W2a; Wt = W2at; N = 256; off = idx - 65536; }
    else if (idx < 163840) { W = W1b; Wt = W1bt; N = 128; off = idx - 131072; }
    else                   { W = W2b; Wt = W2bt; N = 128; off = idx - 163840; }
    int n = off >> 8, k = off & 255;
    Wt[off] = f2bf(W[k * N + n]);
    if (cb < 16)            rowsum[cb * 256 + tid] = 0.f;
    else if (cb < 32)       colsum[(cb - 16) * 256 + tid] = 0.f;
    return;
  }
  // ---- aggregate path ----
  int b = blk >> 1;
  const int *nb, *rl, *mk;
  u16* out;
  if ((blk & 1) == 0) { nb = nb1; rl = rl1; mk = mk1; out = v1; }
  else                { nb = nb2; rl = rl2; mk = mk2; out = v2; }
  int g = tid >> 6, c = tid & 63;

  float ax = 0.f, ay = 0.f, az = 0.f, aw = 0.f;
  int cnt = 0;
#pragma unroll
  for (int kk = 0; kk < 8; ++kk) {
    int k = kk * 4 + g;
    if (mk[b * KK + k]) {                       // wave-uniform branch
      int nid = nb[b * KK + k];
      int rid = rl[b * KK + k];
      float4 m = *(const float4*)(nf + (size_t)nid * DD + c * 4);
      float4 r = *(const float4*)(rel + (size_t)rid * DD + c * 4);
      ax += m.x + r.x; ay += m.y + r.y; az += m.z + r.z; aw += m.w + r.w;
      cnt++;
    }
  }
  __shared__ float sbuf[4][64][4];
  __shared__ int scnt[4];
  sbuf[g][c][0] = ax; sbuf[g][c][1] = ay; sbuf[g][c][2] = az; sbuf[g][c][3] = aw;
  if (c == 0) scnt[g] = cnt;
  __syncthreads();
  if (g == 0) {
    float sx = sbuf[0][c][0] + sbuf[1][c][0] + sbuf[2][c][0] + sbuf[3][c][0];
    float sy = sbuf[0][c][1] + sbuf[1][c][1] + sbuf[2][c][1] + sbuf[3][c][1];
    float sz = sbuf[0][c][2] + sbuf[1][c][2] + sbuf[2][c][2] + sbuf[3][c][2];
    float sw = sbuf[0][c][3] + sbuf[1][c][3] + sbuf[2][c][3] + sbuf[3][c][3];
    int tot = scnt[0] + scnt[1] + scnt[2] + scnt[3];
    float rx, ry, rz, rw;
    if (tot > 0) {
      float inv = 1.0f / (float)tot;
      rx = sx * inv; ry = sy * inv; rz = sz * inv; rw = sw * inv;
    } else {
      float4 s = *(const float4*)(nf + (size_t)self_ids[b] * DD + c * 4);
      rx = s.x; ry = s.y; rz = s.z; rw = s.w;
    }
    union { u16 us[4]; uint2 u2; } pk;
    pk.us[0] = f2bf(rx); pk.us[1] = f2bf(ry); pk.us[2] = f2bf(rz); pk.us[3] = f2bf(rw);
    *(uint2*)(out + (size_t)b * DD + c * 4) = pk.u2;
  }
}

// ---------------------------------------------------------------------------
// Fused projection + row-normalize:
//   z = relu(v @ Wa + ba) @ Wb + bb;  z_bf16 = z / ||z||_row
// Block = 128 rows x all 128 z-cols -> norm is block-local.
// grid (BB/128, 2): blockIdx.y = view.
// ---------------------------------------------------------------------------
__global__ void __launch_bounds__(256, 1)
proj_fused(const u16* __restrict__ v1, const u16* __restrict__ v2,
           const u16* __restrict__ W1at, const u16* __restrict__ W2at,
           const float* __restrict__ b1a, const float* __restrict__ b2a,
           const u16* __restrict__ W1bt, const u16* __restrict__ W2bt,
           const float* __restrict__ b1b, const float* __restrict__ b2b,
           u16* __restrict__ z1, u16* __restrict__ z2) {
  const u16 *v, *Wat, *Wbt;
  const float *ba, *bb;
  u16* z;
  if (blockIdx.y == 0) { v = v1; Wat = W1at; ba = b1a; Wbt = W1bt; bb = b1b; z = z1; }
  else                 { v = v2; Wat = W2at; ba = b2a; Wbt = W2bt; bb = b2b; z = z2; }
  __shared__ u16 hs[128 * HS];
  __shared__ float ns[128][2];
  int tid = threadIdx.x;
  int lane = tid & 63, wid = tid >> 6;
  int m16 = lane & 15, q = lane >> 4;
  int rh = wid >> 1, ch = wid & 1;
  int M0 = blockIdx.x * 128;
  int rowl = rh * 64;                 // block-local row base for this wave

  // ---- phase 1: h = relu(v @ Wa + ba), two 128-col tiles -> LDS ----
  for (int nt = 0; nt < 2; ++nt) {
    int colb = nt * 128 + ch * 64;
    floatx4 acc[4][4] = {};
    for (int k0 = 0; k0 < DD; k0 += 32) {
      short8 a[4], b[4];
#pragma unroll
      for (int i = 0; i < 4; i++)
        a[i] = *(const short8*)(v + (size_t)(M0 + rowl + i * 16 + m16) * DD + k0 + q * 8);
#pragma unroll
      for (int j = 0; j < 4; j++)
        b[j] = *(const short8*)(Wat + (size_t)(colb + j * 16 + m16) * DD + k0 + q * 8);
#pragma unroll
      for (int i = 0; i < 4; i++)
#pragma unroll
        for (int j = 0; j < 4; j++)
          acc[i][j] = __builtin_amdgcn_mfma_f32_16x16x32_bf16(a[i], b[j], acc[i][j], 0, 0, 0);
    }
#pragma unroll
    for (int i = 0; i < 4; i++)
#pragma unroll
      for (int j = 0; j < 4; j++) {
        int col = colb + j * 16 + m16;
        float bv = ba[col];
#pragma unroll
        for (int r = 0; r < 4; r++) {
          int row = rowl + i * 16 + q * 4 + r;
          hs[row * HS + col] = f2bf(fmaxf(acc[i][j][r] + bv, 0.f));
        }
      }
  }
  __syncthreads();

  // ---- phase 2: z = h @ Wb + bb (128 cols), keep fp32 in registers ----
  int colb = ch * 64;
  floatx4 acc[4][4] = {};
  for (int k0 = 0; k0 < DD; k0 += 32) {
    short8 a[4], b[4];
#pragma unroll
    for (int i = 0; i < 4; i++)
      a[i] = *(const short8*)(hs + (rowl + i * 16 + m16) * HS + k0 + q * 8);
#pragma unroll
    for (int j = 0; j < 4; j++)
      b[j] = *(const short8*)(Wbt + (size_t)(colb + j * 16 + m16) * DD + k0 + q * 8);
#pragma unroll
    for (int i = 0; i < 4; i++)
#pragma unroll
      for (int j = 0; j < 4; j++)
        acc[i][j] = __builtin_amdgcn_mfma_f32_16x16x32_bf16(a[i], b[j], acc[i][j], 0, 0, 0);
  }
  // add bias, accumulate row sum-of-squares for this col-half
  float ss[4][4];
#pragma unroll
  for (int i = 0; i < 4; i++)
#pragma unroll
    for (int r = 0; r < 4; r++) ss[i][r] = 0.f;
#pragma unroll
  for (int j = 0; j < 4; j++) {
    float bv = bb[colb + j * 16 + m16];
#pragma unroll
    for (int i = 0; i < 4; i++)
#pragma unroll
      for (int r = 0; r < 4; r++) {
        float zv = acc[i][j][r] + bv;
        acc[i][j][r] = zv;
        ss[i][r] += zv * zv;
      }
  }
#pragma unroll
  for (int off = 1; off <= 8; off <<= 1)
#pragma unroll
    for (int i = 0; i < 4; i++)
#pragma unroll
      for (int r = 0; r < 4; r++) ss[i][r] += __shfl_xor(ss[i][r], off);
  if (m16 == 0) {
#pragma unroll
    for (int i = 0; i < 4; i++)
#pragma unroll
      for (int r = 0; r < 4; r++) ns[rowl + i * 16 + q * 4 + r][ch] = ss[i][r];
  }
  __syncthreads();
#pragma unroll
  for (int i = 0; i < 4; i++)
#pragma unroll
    for (int r = 0; r < 4; r++) {
      int row = rowl + i * 16 + q * 4 + r;
      float rn = rsqrtf(ns[row][0] + ns[row][1]);
#pragma unroll
      for (int j = 0; j < 4; j++)
        z[(size_t)(M0 + row) * ZD + colb + j * 16 + m16] = f2bf(acc[i][j][r] * rn);
    }
}

// ---------------------------------------------------------------------------
// sim + diag: exp((z1n.z2n^T)/TEMP) row/col sums via shuffle + one atomic per
// row/col per wave; diagonal tiles write diag = sim_ii (pre-exp, fp32).
// NO device-scope fences here (round-4 lesson: per-wave __threadfence() on
// 8-XCD parts serializes L2 writebacks -> 9x kernel slowdown).
// ---------------------------------------------------------------------------
__global__ void __launch_bounds__(256, 2)
sim_kernel(const u16* __restrict__ z1, const u16* __restrict__ z2,
           float* __restrict__ rowsum, float* __restrict__ colsum,
           float* __restrict__ diag) {
  int tid = threadIdx.x;
  int lane = tid & 63, wid = tid >> 6;
  int m16 = lane & 15, q = lane >> 4;
  int rowbase = blockIdx.x * 128 + (wid >> 1) * 64;
  int colbase = blockIdx.y * 128 + (wid & 1) * 64;
  floatx4 acc[4][4] = {};
  for (int k0 = 0; k0 < ZD; k0 += 32) {
    short8 a[4], b[4];
#pragma unroll
    for (int i = 0; i < 4; i++)
      a[i] = *(const short8*)(z1 + (size_t)(rowbase + i * 16 + m16) * ZD + k0 + q * 8);
#pragma unroll
    for (int j = 0; j < 4; j++)
      b[j] = *(const short8*)(z2 + (size_t)(colbase + j * 16 + m16) * ZD + k0 + q * 8);
#pragma unroll
    for (int i = 0; i < 4; i++)
#pragma unroll
      for (int j = 0; j < 4; j++)
        acc[i][j] = __builtin_amdgcn_mfma_f32_16x16x32_bf16(a[i], b[j], acc[i][j], 0, 0, 0);
  }
  if (rowbase == colbase) {
#pragma unroll
    for (int i = 0; i < 4; i++)
#pragma unroll
      for (int r = 0; r < 4; r++)
        if (m16 == q * 4 + r)
          diag[rowbase + i * 16 + m16] = acc[i][i][r] * INVTEMP;
  }
  float rowacc[4][4] = {};   // [i][r]
  float colacc[4] = {};      // [j]
#pragma unroll
  for (int i = 0; i < 4; i++)
#pragma unroll
    for (int j = 0; j < 4; j++)
#pragma unroll
      for (int r = 0; r < 4; r++) {
        float e = __expf(acc[i][j][r] * INVTEMP);
        rowacc[i][r] += e;
        colacc[j] += e;
      }
#pragma unroll
  for (int off = 1; off <= 8; off <<= 1)
#pragma unroll
    for (int i = 0; i < 4; i++)
#pragma unroll
      for (int r = 0; r < 4; r++) rowacc[i][r] += __shfl_xor(rowacc[i][r], off);
  if (m16 == 0) {
#pragma unroll
    for (int i = 0; i < 4; i++)
#pragma unroll
      for (int r = 0; r < 4; r++)
        atomicAdd(&rowsum[rowbase + i * 16 + q * 4 + r], rowacc[i][r]);
  }
#pragma unroll
  for (int off = 16; off <= 32; off <<= 1)
#pragma unroll
    for (int j = 0; j < 4; j++) colacc[j] += __shfl_xor(colacc[j], off);
  if (q == 0) {
#pragma unroll
    for (int j = 0; j < 4; j++)
      atomicAdd(&colsum[colbase + j * 16 + m16], colacc[j]);
  }
}

// ---------------------------------------------------------------------------
// loss = mean_i( 0.5*(log(rowsum_i)+log(colsum_i)) - diag_i )
// ---------------------------------------------------------------------------
__global__ void loss_kernel(const float* __restrict__ rowsum, const float* __restrict__ colsum,
                            const float* __restrict__ diag, float* __restrict__ out) {
  int tid = threadIdx.x;
  float acc = 0.f;
  for (int i = tid; i < BB; i += 256)
    acc += 0.5f * (__logf(rowsum[i]) + __logf(colsum[i])) - diag[i];
#pragma unroll
  for (int off = 1; off < 64; off <<= 1) acc += __shfl_xor(acc, off);
  __shared__ float sbuf[4];
  if ((tid & 63) == 0) sbuf[tid >> 6] = acc;
  __syncthreads();
  if (tid == 0) out[0] = (sbuf[0] + sbuf[1] + sbuf[2] + sbuf[3]) * (1.0f / BB);
}

extern "C" void kernel_launch(void* const* d_in, const int* in_sizes, int n_in,
                              void* d_out, int out_size, void* d_ws, size_t ws_size,
                              hipStream_t stream) {
  const float* nf  = (const float*)d_in[0];
  const float* rel = (const float*)d_in[1];
  const int* nb1 = (const int*)d_in[2];
  const int* rl1 = (const int*)d_in[3];
  const int* mk1 = (const int*)d_in[4];
  const int* nb2 = (const int*)d_in[5];
  const int* rl2 = (const int*)d_in[6];
  const int* mk2 = (const int*)d_in[7];
  const int* self_ids = (const int*)d_in[8];
  const float* W1a = (const float*)d_in[9];
  const float* b1a = (const float*)d_in[10];
  const float* W1b = (const float*)d_in[11];
  const float* b1b = (const float*)d_in[12];
  const float* W2a = (const float*)d_in[13];
  const float* b2a = (const float*)d_in[14];
  const float* W2b = (const float*)d_in[15];
  const float* b2b = (const float*)d_in[16];

  char* ws = (char*)d_ws;
  u16* v1   = (u16*)ws;                 ws += (size_t)BB * DD * 2;
  u16* v2   = (u16*)ws;                 ws += (size_t)BB * DD * 2;
  u16* z1   = (u16*)ws;                 ws += (size_t)BB * ZD * 2;
  u16* z2   = (u16*)ws;                 ws += (size_t)BB * ZD * 2;
  u16* W1at = (u16*)ws;                 ws += (size_t)DD * DD * 2;
  u16* W2at = (u16*)ws;                 ws += (size_t)DD * DD * 2;
  u16* W1bt = (u16*)ws;                 ws += (size_t)ZD * DD * 2;
  u16* W2bt = (u16*)ws;                 ws += (size_t)ZD * DD * 2;
  float* rowsum = (float*)ws;           ws += (size_t)BB * 4;
  float* colsum = (float*)ws;           ws += (size_t)BB * 4;
  float* diag   = (float*)ws;           ws += (size_t)BB * 4;

  prep_kernel<<<2 * BB + 768, 256, 0, stream>>>(nf, rel, nb1, rl1, mk1, nb2, rl2, mk2,
                                                self_ids, v1, v2,
                                                W1a, W2a, W1b, W2b,
                                                W1at, W2at, W1bt, W2bt,
                                                rowsum, colsum);
  proj_fused<<<dim3(BB / 128, 2), 256, 0, stream>>>(v1, v2, W1at, W2at, b1a, b2a,
                                                    W1bt, W2bt, b1b, b2b, z1, z2);
  sim_kernel<<<dim3(BB / 128, BB / 128), 256, 0, stream>>>(z1, z2, rowsum, colsum, diag);
  loss_kernel<<<1, 256, 0, stream>>>(rowsum, colsum, diag, (float*)d_out);
}

// Round 6
// 237.065 us; speedup vs baseline: 1.3189x; 1.0500x over previous
//
#include <hip/hip_runtime.h>
#include <hip/hip_bf16.h>
#include <math.h>

#define NN 100000
#define DD 256
#define BB 4096
#define KK 32
#define ZD 128
#define INVTEMP (1.0f/0.07f)
#define HS 264   // LDS row stride for h tile (bf16): 256 + 8 pad -> 2-way conflicts only

typedef unsigned short u16;
typedef __attribute__((ext_vector_type(8))) short short8;   // 8 x bf16 (4 VGPRs)
typedef __attribute__((ext_vector_type(4))) float floatx4;  // MFMA acc

__device__ inline u16 f2bf(float f) {
  __hip_bfloat16 h = __float2bfloat16(f);
  return *reinterpret_cast<u16*>(&h);
}

// ---------------------------------------------------------------------------
// prep: blocks [0, 8192) = aggregate (b = blk>>1, view = blk&1);
//       blocks [8192, 8960) = weight convert/transpose + zero rowsum/colsum.
// Aggregate: 4 k-groups x 64 lanes; group g owns slots k = 8g..8g+7.
// All conditional loads hoisted ahead of use -> ~8-16 loads in flight per
// wave (latency amortized) instead of load->use serialization per slot.
// ---------------------------------------------------------------------------
__global__ void prep_kernel(const float* __restrict__ nf,
                            const float* __restrict__ rel,
                            const int* __restrict__ nb1, const int* __restrict__ rl1, const int* __restrict__ mk1,
                            const int* __restrict__ nb2, const int* __restrict__ rl2, const int* __restrict__ mk2,
                            const int* __restrict__ self_ids,
                            u16* __restrict__ v1, u16* __restrict__ v2,
                            const float* __restrict__ W1a, const float* __restrict__ W2a,
                            const float* __restrict__ W1b, const float* __restrict__ W2b,
                            u16* __restrict__ W1at, u16* __restrict__ W2at,
                            u16* __restrict__ W1bt, u16* __restrict__ W2bt,
                            float* __restrict__ rowsum, float* __restrict__ colsum) {
  int blk = blockIdx.x;
  int tid = threadIdx.x;
  if (blk >= 2 * BB) {
    // ---- weight convert + zero path ----
    int cb = blk - 2 * BB;                       // 0..767
    int idx = cb * 256 + tid;
    const float* W; u16* Wt; int N, off;
    if (idx < 65536)       { W = W1a; Wt = W1at; N = 256; off = idx; }
    else if (idx < 131072) { W = W2a; Wt = W2at; N = 256; off = idx - 65536; }
    else if (idx < 163840) { W = W1b; Wt = W1bt; N = 128; off = idx - 131072; }
    else                   { W = W2b; Wt = W2bt; N = 128; off = idx - 163840; }
    int n = off >> 8, k = off & 255;
    Wt[off] = f2bf(W[k * N + n]);
    if (cb < 16)            rowsum[cb * 256 + tid] = 0.f;
    else if (cb < 32)       colsum[(cb - 16) * 256 + tid] = 0.f;
    return;
  }
  // ---- aggregate path ----
  int b = blk >> 1;
  const int *nb, *rl, *mk;
  u16* out;
  if ((blk & 1) == 0) { nb = nb1; rl = rl1; mk = mk1; out = v1; }
  else                { nb = nb2; rl = rl2; mk = mk2; out = v2; }
  int g = tid >> 6, c = tid & 63;
  int kbase = b * KK + g * 8;

  // wave-uniform index/mask loads (compiler scalarizes)
  int mkv[8], nbv[8], rlv[8];
#pragma unroll
  for (int kk = 0; kk < 8; ++kk) {
    mkv[kk] = mk[kbase + kk];
    nbv[kk] = nb[kbase + kk];
    rlv[kk] = rl[kbase + kk];
  }
  // hoisted conditional loads: issue everything before any use
  float4 rows[8], rrows[8];
#pragma unroll
  for (int kk = 0; kk < 8; ++kk) {
    if (mkv[kk]) {
      rows[kk]  = *(const float4*)(nf  + (size_t)nbv[kk] * DD + c * 4);
      rrows[kk] = *(const float4*)(rel + (size_t)rlv[kk] * DD + c * 4);
    }
  }
  float ax = 0.f, ay = 0.f, az = 0.f, aw = 0.f;
  int cnt = 0;
#pragma unroll
  for (int kk = 0; kk < 8; ++kk) {
    if (mkv[kk]) {
      ax += rows[kk].x + rrows[kk].x;
      ay += rows[kk].y + rrows[kk].y;
      az += rows[kk].z + rrows[kk].z;
      aw += rows[kk].w + rrows[kk].w;
      cnt++;
    }
  }
  __shared__ float sbuf[4][64][4];
  __shared__ int scnt[4];
  sbuf[g][c][0] = ax; sbuf[g][c][1] = ay; sbuf[g][c][2] = az; sbuf[g][c][3] = aw;
  if (c == 0) scnt[g] = cnt;
  __syncthreads();
  if (g == 0) {
    float sx = sbuf[0][c][0] + sbuf[1][c][0] + sbuf[2][c][0] + sbuf[3][c][0];
    float sy = sbuf[0][c][1] + sbuf[1][c][1] + sbuf[2][c][1] + sbuf[3][c][1];
    float sz = sbuf[0][c][2] + sbuf[1][c][2] + sbuf[2][c][2] + sbuf[3][c][2];
    float sw = sbuf[0][c][3] + sbuf[1][c][3] + sbuf[2][c][3] + sbuf[3][c][3];
    int tot = scnt[0] + scnt[1] + scnt[2] + scnt[3];
    float rx, ry, rz, rw;
    if (tot > 0) {
      float inv = 1.0f / (float)tot;
      rx = sx * inv; ry = sy * inv; rz = sz * inv; rw = sw * inv;
    } else {
      float4 s = *(const float4*)(nf + (size_t)self_ids[b] * DD + c * 4);
      rx = s.x; ry = s.y; rz = s.z; rw = s.w;
    }
    union { u16 us[4]; uint2 u2; } pk;
    pk.us[0] = f2bf(rx); pk.us[1] = f2bf(ry); pk.us[2] = f2bf(rz); pk.us[3] = f2bf(rw);
    *(uint2*)(out + (size_t)b * DD + c * 4) = pk.u2;
  }
}

// ---------------------------------------------------------------------------
// Fused projection + row-normalize:
//   z = relu(v @ Wa + ba) @ Wb + bb;  z_bf16 = z / ||z||_row
// Block = 128 rows x all 128 z-cols -> norm is block-local.
// grid (BB/128, 2): blockIdx.y = view.
// ---------------------------------------------------------------------------
__global__ void __launch_bounds__(256, 1)
proj_fused(const u16* __restrict__ v1, const u16* __restrict__ v2,
           const u16* __restrict__ W1at, const u16* __restrict__ W2at,
           const float* __restrict__ b1a, const float* __restrict__ b2a,
           const u16* __restrict__ W1bt, const u16* __restrict__ W2bt,
           const float* __restrict__ b1b, const float* __restrict__ b2b,
           u16* __restrict__ z1, u16* __restrict__ z2) {
  const u16 *v, *Wat, *Wbt;
  const float *ba, *bb;
  u16* z;
  if (blockIdx.y == 0) { v = v1; Wat = W1at; ba = b1a; Wbt = W1bt; bb = b1b; z = z1; }
  else                 { v = v2; Wat = W2at; ba = b2a; Wbt = W2bt; bb = b2b; z = z2; }
  __shared__ u16 hs[128 * HS];
  __shared__ float ns[128][2];
  int tid = threadIdx.x;
  int lane = tid & 63, wid = tid >> 6;
  int m16 = lane & 15, q = lane >> 4;
  int rh = wid >> 1, ch = wid & 1;
  int M0 = blockIdx.x * 128;
  int rowl = rh * 64;                 // block-local row base for this wave

  // ---- phase 1: h = relu(v @ Wa + ba), two 128-col tiles -> LDS ----
  for (int nt = 0; nt < 2; ++nt) {
    int colb = nt * 128 + ch * 64;
    floatx4 acc[4][4] = {};
#pragma unroll
    for (int k0 = 0; k0 < DD; k0 += 32) {
      short8 a[4], b[4];
#pragma unroll
      for (int i = 0; i < 4; i++)
        a[i] = *(const short8*)(v + (size_t)(M0 + rowl + i * 16 + m16) * DD + k0 + q * 8);
#pragma unroll
      for (int j = 0; j < 4; j++)
        b[j] = *(const short8*)(Wat + (size_t)(colb + j * 16 + m16) * DD + k0 + q * 8);
#pragma unroll
      for (int i = 0; i < 4; i++)
#pragma unroll
        for (int j = 0; j < 4; j++)
          acc[i][j] = __builtin_amdgcn_mfma_f32_16x16x32_bf16(a[i], b[j], acc[i][j], 0, 0, 0);
    }
#pragma unroll
    for (int i = 0; i < 4; i++)
#pragma unroll
      for (int j = 0; j < 4; j++) {
        int col = colb + j * 16 + m16;
        float bv = ba[col];
#pragma unroll
        for (int r = 0; r < 4; r++) {
          int row = rowl + i * 16 + q * 4 + r;
          hs[row * HS + col] = f2bf(fmaxf(acc[i][j][r] + bv, 0.f));
        }
      }
  }
  __syncthreads();

  // ---- phase 2: z = h @ Wb + bb (128 cols), keep fp32 in registers ----
  int colb = ch * 64;
  floatx4 acc[4][4] = {};
#pragma unroll
  for (int k0 = 0; k0 < DD; k0 += 32) {
    short8 a[4], b[4];
#pragma unroll
    for (int i = 0; i < 4; i++)
      a[i] = *(const short8*)(hs + (rowl + i * 16 + m16) * HS + k0 + q * 8);
#pragma unroll
    for (int j = 0; j < 4; j++)
      b[j] = *(const short8*)(Wbt + (size_t)(colb + j * 16 + m16) * DD + k0 + q * 8);
#pragma unroll
    for (int i = 0; i < 4; i++)
#pragma unroll
      for (int j = 0; j < 4; j++)
        acc[i][j] = __builtin_amdgcn_mfma_f32_16x16x32_bf16(a[i], b[j], acc[i][j], 0, 0, 0);
  }
  // add bias, accumulate row sum-of-squares for this col-half
  float ss[4][4];
#pragma unroll
  for (int i = 0; i < 4; i++)
#pragma unroll
    for (int r = 0; r < 4; r++) ss[i][r] = 0.f;
#pragma unroll
  for (int j = 0; j < 4; j++) {
    float bv = bb[colb + j * 16 + m16];
#pragma unroll
    for (int i = 0; i < 4; i++)
#pragma unroll
      for (int r = 0; r < 4; r++) {
        float zv = acc[i][j][r] + bv;
        acc[i][j][r] = zv;
        ss[i][r] += zv * zv;
      }
  }
#pragma unroll
  for (int off = 1; off <= 8; off <<= 1)
#pragma unroll
    for (int i = 0; i < 4; i++)
#pragma unroll
      for (int r = 0; r < 4; r++) ss[i][r] += __shfl_xor(ss[i][r], off);
  if (m16 == 0) {
#pragma unroll
    for (int i = 0; i < 4; i++)
#pragma unroll
      for (int r = 0; r < 4; r++) ns[rowl + i * 16 + q * 4 + r][ch] = ss[i][r];
  }
  __syncthreads();
#pragma unroll
  for (int i = 0; i < 4; i++)
#pragma unroll
    for (int r = 0; r < 4; r++) {
      int row = rowl + i * 16 + q * 4 + r;
      float rn = rsqrtf(ns[row][0] + ns[row][1]);
#pragma unroll
      for (int j = 0; j < 4; j++)
        z[(size_t)(M0 + row) * ZD + colb + j * 16 + m16] = f2bf(acc[i][j][r] * rn);
    }
}

// ---------------------------------------------------------------------------
// sim + diag: exp((z1n.z2n^T)/TEMP) row/col sums via shuffle + one atomic per
// row/col per wave; diagonal tiles write diag = sim_ii (pre-exp, fp32).
// NO device-scope fences here (round-4 lesson: per-wave __threadfence() on
// 8-XCD parts serializes L2 writebacks -> 9x kernel slowdown).
// ---------------------------------------------------------------------------
__global__ void __launch_bounds__(256, 2)
sim_kernel(const u16* __restrict__ z1, const u16* __restrict__ z2,
           float* __restrict__ rowsum, float* __restrict__ colsum,
           float* __restrict__ diag) {
  int tid = threadIdx.x;
  int lane = tid & 63, wid = tid >> 6;
  int m16 = lane & 15, q = lane >> 4;
  int rowbase = blockIdx.x * 128 + (wid >> 1) * 64;
  int colbase = blockIdx.y * 128 + (wid & 1) * 64;
  floatx4 acc[4][4] = {};
#pragma unroll
  for (int k0 = 0; k0 < ZD; k0 += 32) {
    short8 a[4], b[4];
#pragma unroll
    for (int i = 0; i < 4; i++)
      a[i] = *(const short8*)(z1 + (size_t)(rowbase + i * 16 + m16) * ZD + k0 + q * 8);
#pragma unroll
    for (int j = 0; j < 4; j++)
      b[j] = *(const short8*)(z2 + (size_t)(colbase + j * 16 + m16) * ZD + k0 + q * 8);
#pragma unroll
    for (int i = 0; i < 4; i++)
#pragma unroll
      for (int j = 0; j < 4; j++)
        acc[i][j] = __builtin_amdgcn_mfma_f32_16x16x32_bf16(a[i], b[j], acc[i][j], 0, 0, 0);
  }
  if (rowbase == colbase) {
#pragma unroll
    for (int i = 0; i < 4; i++)
#pragma unroll
      for (int r = 0; r < 4; r++)
        if (m16 == q * 4 + r)
          diag[rowbase + i * 16 + m16] = acc[i][i][r] * INVTEMP;
  }
  float rowacc[4][4] = {};   // [i][r]
  float colacc[4] = {};      // [j]
#pragma unroll
  for (int i = 0; i < 4; i++)
#pragma unroll
    for (int j = 0; j < 4; j++)
#pragma unroll
      for (int r = 0; r < 4; r++) {
        float e = __expf(acc[i][j][r] * INVTEMP);
        rowacc[i][r] += e;
        colacc[j] += e;
      }
#pragma unroll
  for (int off = 1; off <= 8; off <<= 1)
#pragma unroll
    for (int i = 0; i < 4; i++)
#pragma unroll
      for (int r = 0; r < 4; r++) rowacc[i][r] += __shfl_xor(rowacc[i][r], off);
  if (m16 == 0) {
#pragma unroll
    for (int i = 0; i < 4; i++)
#pragma unroll
      for (int r = 0; r < 4; r++)
        atomicAdd(&rowsum[rowbase + i * 16 + q * 4 + r], rowacc[i][r]);
  }
#pragma unroll
  for (int off = 16; off <= 32; off <<= 1)
#pragma unroll
    for (int j = 0; j < 4; j++) colacc[j] += __shfl_xor(colacc[j], off);
  if (q == 0) {
#pragma unroll
    for (int j = 0; j < 4; j++)
      atomicAdd(&colsum[colbase + j * 16 + m16], colacc[j]);
  }
}

// ---------------------------------------------------------------------------
// loss = mean_i( 0.5*(log(rowsum_i)+log(colsum_i)) - diag_i )
// ---------------------------------------------------------------------------
__global__ void loss_kernel(const float* __restrict__ rowsum, const float* __restrict__ colsum,
                            const float* __restrict__ diag, float* __restrict__ out) {
  int tid = threadIdx.x;
  float acc = 0.f;
  for (int i = tid; i < BB; i += 256)
    acc += 0.5f * (__logf(rowsum[i]) + __logf(colsum[i])) - diag[i];
#pragma unroll
  for (int off = 1; off < 64; off <<= 1) acc += __shfl_xor(acc, off);
  __shared__ float sbuf[4];
  if ((tid & 63) == 0) sbuf[tid >> 6] = acc;
  __syncthreads();
  if (tid == 0) out[0] = (sbuf[0] + sbuf[1] + sbuf[2] + sbuf[3]) * (1.0f / BB);
}

extern "C" void kernel_launch(void* const* d_in, const int* in_sizes, int n_in,
                              void* d_out, int out_size, void* d_ws, size_t ws_size,
                              hipStream_t stream) {
  const float* nf  = (const float*)d_in[0];
  const float* rel = (const float*)d_in[1];
  const int* nb1 = (const int*)d_in[2];
  const int* rl1 = (const int*)d_in[3];
  const int* mk1 = (const int*)d_in[4];
  const int* nb2 = (const int*)d_in[5];
  const int* rl2 = (const int*)d_in[6];
  const int* mk2 = (const int*)d_in[7];
  const int* self_ids = (const int*)d_in[8];
  const float* W1a = (const float*)d_in[9];
  const float* b1a = (const float*)d_in[10];
  const float* W1b = (const float*)d_in[11];
  const float* b1b = (const float*)d_in[12];
  const float* W2a = (const float*)d_in[13];
  const float* b2a = (const float*)d_in[14];
  const float* W2b = (const float*)d_in[15];
  const float* b2b = (const float*)d_in[16];

  char* ws = (char*)d_ws;
  u16* v1   = (u16*)ws;                 ws += (size_t)BB * DD * 2;
  u16* v2   = (u16*)ws;                 ws += (size_t)BB * DD * 2;
  u16* z1   = (u16*)ws;                 ws += (size_t)BB * ZD * 2;
  u16* z2   = (u16*)ws;                 ws += (size_t)BB * ZD * 2;
  u16* W1at = (u16*)ws;                 ws += (size_t)DD * DD * 2;
  u16* W2at = (u16*)ws;                 ws += (size_t)DD * DD * 2;
  u16* W1bt = (u16*)ws;                 ws += (size_t)ZD * DD * 2;
  u16* W2bt = (u16*)ws;                 ws += (size_t)ZD * DD * 2;
  float* rowsum = (float*)ws;           ws += (size_t)BB * 4;
  float* colsum = (float*)ws;           ws += (size_t)BB * 4;
  float* diag   = (float*)ws;           ws += (size_t)BB * 4;

  prep_kernel<<<2 * BB + 768, 256, 0, stream>>>(nf, rel, nb1, rl1, mk1, nb2, rl2, mk2,
                                                self_ids, v1, v2,
                                                W1a, W2a, W1b, W2b,
                                                W1at, W2at, W1bt, W2bt,
                                                rowsum, colsum);
  proj_fused<<<dim3(BB / 128, 2), 256, 0, stream>>>(v1, v2, W1at, W2at, b1a, b2a,
                                                    W1bt, W2bt, b1b, b2b, z1, z2);
  sim_kernel<<<dim3(BB / 128, BB / 128), 256, 0, stream>>>(z1, z2, rowsum, colsum, diag);
  loss_kernel<<<1, 256, 0, stream>>>(rowsum, colsum, diag, (float*)d_out);
}

// Round 7
// 236.421 us; speedup vs baseline: 1.3225x; 1.0027x over previous
//
#include <hip/hip_runtime.h>
#include <hip/hip_bf16.h>
#include <math.h>

#define NN 100000
#define DD 256
#define BB 4096
#define KK 32
#define ZD 128
#define NREL 9
#define INVTEMP (1.0f/0.07f)
#define HS 264   // LDS row stride for h tile (bf16): 256 + 8 pad -> 2-way conflicts only

typedef unsigned short u16;
typedef __attribute__((ext_vector_type(8))) short short8;   // 8 x bf16 (4 VGPRs)
typedef __attribute__((ext_vector_type(4))) float floatx4;  // MFMA acc

__device__ inline u16 f2bf(float f) {
  __hip_bfloat16 h = __float2bfloat16(f);
  return *reinterpret_cast<u16*>(&h);
}

// ---------------------------------------------------------------------------
// prep: blocks [0, 8192) = aggregate (b = blk>>1, view = blk&1);
//       blocks [8192, 8960) = weight convert/transpose + zero rowsum/colsum.
// Aggregate: 4 k-groups x 64 lanes; group g owns slots k = 8g..8g+7.
// nf loads hoisted (latency overlap). rel contribution via relation COUNTS:
// sum_masked rel[rl[k]] == sum_r cnt_r * rel[r]  (9 rows, L1-hot) -> removes
// ~40% of gather-loop VMEM instructions vs per-slot rel loads.
// ---------------------------------------------------------------------------
__global__ void prep_kernel(const float* __restrict__ nf,
                            const float* __restrict__ rel,
                            const int* __restrict__ nb1, const int* __restrict__ rl1, const int* __restrict__ mk1,
                            const int* __restrict__ nb2, const int* __restrict__ rl2, const int* __restrict__ mk2,
                            const int* __restrict__ self_ids,
                            u16* __restrict__ v1, u16* __restrict__ v2,
                            const float* __restrict__ W1a, const float* __restrict__ W2a,
                            const float* __restrict__ W1b, const float* __restrict__ W2b,
                            u16* __restrict__ W1at, u16* __restrict__ W2at,
                            u16* __restrict__ W1bt, u16* __restrict__ W2bt,
                            float* __restrict__ rowsum, float* __restrict__ colsum) {
  int blk = blockIdx.x;
  int tid = threadIdx.x;
  if (blk >= 2 * BB) {
    // ---- weight convert + zero path ----
    int cb = blk - 2 * BB;                       // 0..767
    int idx = cb * 256 + tid;
    const float* W; u16* Wt; int N, off;
    if (idx < 65536)       { W = W1a; Wt = W1at; N = 256; off = idx; }
    else if (idx < 131072) { W = W2a; Wt = W2at; N = 256; off = idx - 65536; }
    else if (idx < 163840) { W = W1b; Wt = W1bt; N = 128; off = idx - 131072; }
    else                   { W = W2b; Wt = W2bt; N = 128; off = idx - 163840; }
    int n = off >> 8, k = off & 255;
    Wt[off] = f2bf(W[k * N + n]);
    if (cb < 16)            rowsum[cb * 256 + tid] = 0.f;
    else if (cb < 32)       colsum[(cb - 16) * 256 + tid] = 0.f;
    return;
  }
  // ---- aggregate path ----
  int b = blk >> 1;
  const int *nb, *rl, *mk;
  u16* out;
  if ((blk & 1) == 0) { nb = nb1; rl = rl1; mk = mk1; out = v1; }
  else                { nb = nb2; rl = rl2; mk = mk2; out = v2; }
  int g = tid >> 6, c = tid & 63;
  int kbase = b * KK + g * 8;

  // wave-uniform index/mask loads (uniform addresses -> scalarized)
  int mkv[8], nbv[8], rlv[8];
#pragma unroll
  for (int kk = 0; kk < 8; ++kk) {
    mkv[kk] = mk[kbase + kk];
    nbv[kk] = nb[kbase + kk];
    rlv[kk] = rl[kbase + kk];
  }
  // hoisted conditional nf loads: issue everything before any use
  float4 rows[8];
#pragma unroll
  for (int kk = 0; kk < 8; ++kk) {
    if (mkv[kk]) rows[kk] = *(const float4*)(nf + (size_t)nbv[kk] * DD + c * 4);
  }
  // per-group relation counts (wave-uniform scalar work)
  int rcnt[NREL];
#pragma unroll
  for (int r = 0; r < NREL; ++r) rcnt[r] = 0;
  float ax = 0.f, ay = 0.f, az = 0.f, aw = 0.f;
  int cnt = 0;
#pragma unroll
  for (int kk = 0; kk < 8; ++kk) {
    if (mkv[kk]) {
      ax += rows[kk].x; ay += rows[kk].y; az += rows[kk].z; aw += rows[kk].w;
      cnt++;
#pragma unroll
      for (int r = 0; r < NREL; ++r) rcnt[r] += (rlv[kk] == r) ? 1 : 0;
    }
  }
  __shared__ float sbuf[4][64][4];
  __shared__ int scnt[4];
  __shared__ int srel[4][NREL];
  sbuf[g][c][0] = ax; sbuf[g][c][1] = ay; sbuf[g][c][2] = az; sbuf[g][c][3] = aw;
  if (c == 0) {
    scnt[g] = cnt;
#pragma unroll
    for (int r = 0; r < NREL; ++r) srel[g][r] = rcnt[r];
  }
  __syncthreads();
  if (g == 0) {
    float sx = sbuf[0][c][0] + sbuf[1][c][0] + sbuf[2][c][0] + sbuf[3][c][0];
    float sy = sbuf[0][c][1] + sbuf[1][c][1] + sbuf[2][c][1] + sbuf[3][c][1];
    float sz = sbuf[0][c][2] + sbuf[1][c][2] + sbuf[2][c][2] + sbuf[3][c][2];
    float sw = sbuf[0][c][3] + sbuf[1][c][3] + sbuf[2][c][3] + sbuf[3][c][3];
    int tot = scnt[0] + scnt[1] + scnt[2] + scnt[3];
    // rel contribution: sum_r cnt_r * rel[r]  (wave-uniform conditions)
#pragma unroll
    for (int r = 0; r < NREL; ++r) {
      int cr = srel[0][r] + srel[1][r] + srel[2][r] + srel[3][r];
      if (cr > 0) {
        float4 rr = *(const float4*)(rel + (size_t)r * DD + c * 4);
        float fc = (float)cr;
        sx += fc * rr.x; sy += fc * rr.y; sz += fc * rr.z; sw += fc * rr.w;
      }
    }
    float rx, ry, rz, rw;
    if (tot > 0) {
      float inv = 1.0f / (float)tot;
      rx = sx * inv; ry = sy * inv; rz = sz * inv; rw = sw * inv;
    } else {
      float4 s = *(const float4*)(nf + (size_t)self_ids[b] * DD + c * 4);
      rx = s.x; ry = s.y; rz = s.z; rw = s.w;
    }
    union { u16 us[4]; uint2 u2; } pk;
    pk.us[0] = f2bf(rx); pk.us[1] = f2bf(ry); pk.us[2] = f2bf(rz); pk.us[3] = f2bf(rw);
    *(uint2*)(out + (size_t)b * DD + c * 4) = pk.u2;
  }
}

// ---------------------------------------------------------------------------
// Fused projection + row-normalize:
//   z = relu(v @ Wa + ba) @ Wb + bb;  z_bf16 = z / ||z||_row
// Block = 128 rows x all 128 z-cols -> norm is block-local.
// grid (BB/128, 2): blockIdx.y = view.
// ---------------------------------------------------------------------------
__global__ void __launch_bounds__(256, 1)
proj_fused(const u16* __restrict__ v1, const u16* __restrict__ v2,
           const u16* __restrict__ W1at, const u16* __restrict__ W2at,
           const float* __restrict__ b1a, const float* __restrict__ b2a,
           const u16* __restrict__ W1bt, const u16* __restrict__ W2bt,
           const float* __restrict__ b1b, const float* __restrict__ b2b,
           u16* __restrict__ z1, u16* __restrict__ z2) {
  const u16 *v, *Wat, *Wbt;
  const float *ba, *bb;
  u16* z;
  if (blockIdx.y == 0) { v = v1; Wat = W1at; ba = b1a; Wbt = W1bt; bb = b1b; z = z1; }
  else                 { v = v2; Wat = W2at; ba = b2a; Wbt = W2bt; bb = b2b; z = z2; }
  __shared__ u16 hs[128 * HS];
  __shared__ float ns[128][2];
  int tid = threadIdx.x;
  int lane = tid & 63, wid = tid >> 6;
  int m16 = lane & 15, q = lane >> 4;
  int rh = wid >> 1, ch = wid & 1;
  int M0 = blockIdx.x * 128;
  int rowl = rh * 64;                 // block-local row base for this wave

  // ---- phase 1: h = relu(v @ Wa + ba), two 128-col tiles -> LDS ----
  for (int nt = 0; nt < 2; ++nt) {
    int colb = nt * 128 + ch * 64;
    floatx4 acc[4][4] = {};
#pragma unroll
    for (int k0 = 0; k0 < DD; k0 += 32) {
      short8 a[4], b[4];
#pragma unroll
      for (int i = 0; i < 4; i++)
        a[i] = *(const short8*)(v + (size_t)(M0 + rowl + i * 16 + m16) * DD + k0 + q * 8);
#pragma unroll
      for (int j = 0; j < 4; j++)
        b[j] = *(const short8*)(Wat + (size_t)(colb + j * 16 + m16) * DD + k0 + q * 8);
#pragma unroll
      for (int i = 0; i < 4; i++)
#pragma unroll
        for (int j = 0; j < 4; j++)
          acc[i][j] = __builtin_amdgcn_mfma_f32_16x16x32_bf16(a[i], b[j], acc[i][j], 0, 0, 0);
    }
#pragma unroll
    for (int i = 0; i < 4; i++)
#pragma unroll
      for (int j = 0; j < 4; j++) {
        int col = colb + j * 16 + m16;
        float bv = ba[col];
#pragma unroll
        for (int r = 0; r < 4; r++) {
          int row = rowl + i * 16 + q * 4 + r;
          hs[row * HS + col] = f2bf(fmaxf(acc[i][j][r] + bv, 0.f));
        }
      }
  }
  __syncthreads();

  // ---- phase 2: z = h @ Wb + bb (128 cols), keep fp32 in registers ----
  int colb = ch * 64;
  floatx4 acc[4][4] = {};
#pragma unroll
  for (int k0 = 0; k0 < DD; k0 += 32) {
    short8 a[4], b[4];
#pragma unroll
    for (int i = 0; i < 4; i++)
      a[i] = *(const short8*)(hs + (rowl + i * 16 + m16) * HS + k0 + q * 8);
#pragma unroll
    for (int j = 0; j < 4; j++)
      b[j] = *(const short8*)(Wbt + (size_t)(colb + j * 16 + m16) * DD + k0 + q * 8);
#pragma unroll
    for (int i = 0; i < 4; i++)
#pragma unroll
      for (int j = 0; j < 4; j++)
        acc[i][j] = __builtin_amdgcn_mfma_f32_16x16x32_bf16(a[i], b[j], acc[i][j], 0, 0, 0);
  }
  // add bias, accumulate row sum-of-squares for this col-half
  float ss[4][4];
#pragma unroll
  for (int i = 0; i < 4; i++)
#pragma unroll
    for (int r = 0; r < 4; r++) ss[i][r] = 0.f;
#pragma unroll
  for (int j = 0; j < 4; j++) {
    float bv = bb[colb + j * 16 + m16];
#pragma unroll
    for (int i = 0; i < 4; i++)
#pragma unroll
      for (int r = 0; r < 4; r++) {
        float zv = acc[i][j][r] + bv;
        acc[i][j][r] = zv;
        ss[i][r] += zv * zv;
      }
  }
#pragma unroll
  for (int off = 1; off <= 8; off <<= 1)
#pragma unroll
    for (int i = 0; i < 4; i++)
#pragma unroll
      for (int r = 0; r < 4; r++) ss[i][r] += __shfl_xor(ss[i][r], off);
  if (m16 == 0) {
#pragma unroll
    for (int i = 0; i < 4; i++)
#pragma unroll
      for (int r = 0; r < 4; r++) ns[rowl + i * 16 + q * 4 + r][ch] = ss[i][r];
  }
  __syncthreads();
#pragma unroll
  for (int i = 0; i < 4; i++)
#pragma unroll
    for (int r = 0; r < 4; r++) {
      int row = rowl + i * 16 + q * 4 + r;
      float rn = rsqrtf(ns[row][0] + ns[row][1]);
#pragma unroll
      for (int j = 0; j < 4; j++)
        z[(size_t)(M0 + row) * ZD + colb + j * 16 + m16] = f2bf(acc[i][j][r] * rn);
    }
}

// ---------------------------------------------------------------------------
// sim + diag: exp((z1n.z2n^T)/TEMP) row/col sums via shuffle + one atomic per
// row/col per wave; diagonal tiles write diag = sim_ii (pre-exp, fp32).
// NO device-scope fences here (round-4 lesson: per-wave __threadfence() on
// 8-XCD parts serializes L2 writebacks -> 9x kernel slowdown).
// ---------------------------------------------------------------------------
__global__ void __launch_bounds__(256, 2)
sim_kernel(const u16* __restrict__ z1, const u16* __restrict__ z2,
           float* __restrict__ rowsum, float* __restrict__ colsum,
           float* __restrict__ diag) {
  int tid = threadIdx.x;
  int lane = tid & 63, wid = tid >> 6;
  int m16 = lane & 15, q = lane >> 4;
  int rowbase = blockIdx.x * 128 + (wid >> 1) * 64;
  int colbase = blockIdx.y * 128 + (wid & 1) * 64;
  floatx4 acc[4][4] = {};
#pragma unroll
  for (int k0 = 0; k0 < ZD; k0 += 32) {
    short8 a[4], b[4];
#pragma unroll
    for (int i = 0; i < 4; i++)
      a[i] = *(const short8*)(z1 + (size_t)(rowbase + i * 16 + m16) * ZD + k0 + q * 8);
#pragma unroll
    for (int j = 0; j < 4; j++)
      b[j] = *(const short8*)(z2 + (size_t)(colbase + j * 16 + m16) * ZD + k0 + q * 8);
#pragma unroll
    for (int i = 0; i < 4; i++)
#pragma unroll
      for (int j = 0; j < 4; j++)
        acc[i][j] = __builtin_amdgcn_mfma_f32_16x16x32_bf16(a[i], b[j], acc[i][j], 0, 0, 0);
  }
  if (rowbase == colbase) {
#pragma unroll
    for (int i = 0; i < 4; i++)
#pragma unroll
      for (int r = 0; r < 4; r++)
        if (m16 == q * 4 + r)
          diag[rowbase + i * 16 + m16] = acc[i][i][r] * INVTEMP;
  }
  float rowacc[4][4] = {};   // [i][r]
  float colacc[4] = {};      // [j]
#pragma unroll
  for (int i = 0; i < 4; i++)
#pragma unroll
    for (int j = 0; j < 4; j++)
#pragma unroll
      for (int r = 0; r < 4; r++) {
        float e = __expf(acc[i][j][r] * INVTEMP);
        rowacc[i][r] += e;
        colacc[j] += e;
      }
#pragma unroll
  for (int off = 1; off <= 8; off <<= 1)
#pragma unroll
    for (int i = 0; i < 4; i++)
#pragma unroll
      for (int r = 0; r < 4; r++) rowacc[i][r] += __shfl_xor(rowacc[i][r], off);
  if (m16 == 0) {
#pragma unroll
    for (int i = 0; i < 4; i++)
#pragma unroll
      for (int r = 0; r < 4; r++)
        atomicAdd(&rowsum[rowbase + i * 16 + q * 4 + r], rowacc[i][r]);
  }
#pragma unroll
  for (int off = 16; off <= 32; off <<= 1)
#pragma unroll
    for (int j = 0; j < 4; j++) colacc[j] += __shfl_xor(colacc[j], off);
  if (q == 0) {
#pragma unroll
    for (int j = 0; j < 4; j++)
      atomicAdd(&colsum[colbase + j * 16 + m16], colacc[j]);
  }
}

// ---------------------------------------------------------------------------
// loss = mean_i( 0.5*(log(rowsum_i)+log(colsum_i)) - diag_i )
// ---------------------------------------------------------------------------
__global__ void loss_kernel(const float* __restrict__ rowsum, const float* __restrict__ colsum,
                            const float* __restrict__ diag, float* __restrict__ out) {
  int tid = threadIdx.x;
  float acc = 0.f;
  for (int i = tid; i < BB; i += 256)
    acc += 0.5f * (__logf(rowsum[i]) + __logf(colsum[i])) - diag[i];
#pragma unroll
  for (int off = 1; off < 64; off <<= 1) acc += __shfl_xor(acc, off);
  __shared__ float sbuf[4];
  if ((tid & 63) == 0) sbuf[tid >> 6] = acc;
  __syncthreads();
  if (tid == 0) out[0] = (sbuf[0] + sbuf[1] + sbuf[2] + sbuf[3]) * (1.0f / BB);
}

extern "C" void kernel_launch(void* const* d_in, const int* in_sizes, int n_in,
                              void* d_out, int out_size, void* d_ws, size_t ws_size,
                              hipStream_t stream) {
  const float* nf  = (const float*)d_in[0];
  const float* rel = (const float*)d_in[1];
  const int* nb1 = (const int*)d_in[2];
  const int* rl1 = (const int*)d_in[3];
  const int* mk1 = (const int*)d_in[4];
  const int* nb2 = (const int*)d_in[5];
  const int* rl2 = (const int*)d_in[6];
  const int* mk2 = (const int*)d_in[7];
  const int* self_ids = (const int*)d_in[8];
  const float* W1a = (const float*)d_in[9];
  const float* b1a = (const float*)d_in[10];
  const float* W1b = (const float*)d_in[11];
  const float* b1b = (const float*)d_in[12];
  const float* W2a = (const float*)d_in[13];
  const float* b2a = (const float*)d_in[14];
  const float* W2b = (const float*)d_in[15];
  const float* b2b = (const float*)d_in[16];

  char* ws = (char*)d_ws;
  u16* v1   = (u16*)ws;                 ws += (size_t)BB * DD * 2;
  u16* v2   = (u16*)ws;                 ws += (size_t)BB * DD * 2;
  u16* z1   = (u16*)ws;                 ws += (size_t)BB * ZD * 2;
  u16* z2   = (u16*)ws;                 ws += (size_t)BB * ZD * 2;
  u16* W1at = (u16*)ws;                 ws += (size_t)DD * DD * 2;
  u16* W2at = (u16*)ws;                 ws += (size_t)DD * DD * 2;
  u16* W1bt = (u16*)ws;                 ws += (size_t)ZD * DD * 2;
  u16* W2bt = (u16*)ws;                 ws += (size_t)ZD * DD * 2;
  float* rowsum = (float*)ws;           ws += (size_t)BB * 4;
  float* colsum = (float*)ws;           ws += (size_t)BB * 4;
  float* diag   = (float*)ws;           ws += (size_t)BB * 4;

  prep_kernel<<<2 * BB + 768, 256, 0, stream>>>(nf, rel, nb1, rl1, mk1, nb2, rl2, mk2,
                                                self_ids, v1, v2,
                                                W1a, W2a, W1b, W2b,
                                                W1at, W2at, W1bt, W2bt,
                                                rowsum, colsum);
  proj_fused<<<dim3(BB / 128, 2), 256, 0, stream>>>(v1, v2, W1at, W2at, b1a, b2a,
                                                    W1bt, W2bt, b1b, b2b, z1, z2);
  sim_kernel<<<dim3(BB / 128, BB / 128), 256, 0, stream>>>(z1, z2, rowsum, colsum, diag);
  loss_kernel<<<1, 256, 0, stream>>>(rowsum, colsum, diag, (float*)d_out);
}